// Round 11
// baseline (156.701 us; speedup 1.0000x reference)
//
#include <hip/hip_runtime.h>

// PtConv: B=8, N=8192, C_IN=64, C_OUT=128, K=16, M=16, DIM=3
#define BATCH 8
#define NPTS  8192
#define CIN   64
#define COUT  128
#define KNN   16
#define MD    16
#define PTS   16            // mono fallback points/block
#define PTSC  32            // conv points per TILE (block = 2 tiles = 64 points)
#define DT_STR 264          // mono fallback only
#define AGG_STRIDE 1032     // s_agg per-point stride (shorts); 516 dw == 4 mod 32

#define NWT    (COUT * CIN * MD)          // 131072 bf16
#define NFBF   (BATCH * NPTS * CIN)       // 4194304 bf16
#define NPTS_G (BATCH * NPTS)             // 65536

typedef __attribute__((ext_vector_type(8))) short short8;
typedef __attribute__((ext_vector_type(4))) short short4v;
typedef __attribute__((ext_vector_type(4))) float f32x4;
typedef __attribute__((ext_vector_type(2))) float f32x2;

// RNE f32->bf16 bit-hack (round-4-verified). NOTE r8: the native __bf16 cast
// REGRESSED (83.5->97.3us) despite fewer VALU ops — these independent int ops
// overlap stall cycles; do not "optimize" this again.
__device__ __forceinline__ short f2bf(float f) {
  unsigned u = __float_as_uint(f);
  u = (u + 0x7fffu + ((u >> 16) & 1u)) >> 16;   // RNE
  return (short)u;
}

// prep (mode 3): Wt = bf16 W^T in WAVE-COALESCED layout: 16B chunk
//   L = ((wv*32 + kb)*16 + lrow)*4 + quad   holds  Wt_old[co=wv*16+lrow][o=kb*32+quad*8..+8]
// so a conv wave's per-kb B-fragment load is one contiguous 1KB line (r9: -30% conv).
// k-slot permutation o->k matches conv s_agg layout. fbf = channel-interleaved bf16
// features; l2bf/l3bf = bf16 MLP weights; Gc4 = collapsed layer-1; out tail = opts copy.
__global__ __launch_bounds__(256) void prep_kernel(
    const float* __restrict__ weight, const float* __restrict__ opts,
    const float* __restrict__ feats, const float* __restrict__ centers,
    const float* __restrict__ l1_w, const float* __restrict__ l1_b,
    const float* __restrict__ l2_w, const float* __restrict__ l3_w,
    short* __restrict__ Wt, short* __restrict__ fbf,
    short* __restrict__ l2bf, short* __restrict__ l3bf, float* __restrict__ Gc4,
    float* __restrict__ out_tail, int mode) {
  int tid = blockIdx.x * 256 + threadIdx.x;
  if (mode >= 1 && tid < NWT) {
    int co, o;
    if (mode == 3) {
      // decode coalesced slot: tid = (((wv*32+kb)*16+lrow)*4+quad)*8 + j
      int j = tid & 7, quad = (tid >> 3) & 3, lrow = (tid >> 5) & 15;
      int kb = (tid >> 9) & 31, wv = tid >> 14;
      co = wv * 16 + lrow;
      o = kb * 32 + quad * 8 + j;
    } else {
      co = tid >> 10;
      o = tid & 1023;
    }
    int k;
    if (mode == 3) {  // slot o = ct*256 + m*16 + q*4 + r  holds  k = ct*256 + q*64 + r*16 + m
      int r = o & 3, q = (o >> 2) & 3, m = (o >> 4) & 15, ct = o >> 8;
      k = ct * 256 + q * 64 + r * 16 + m;
    } else {
      k = o;
    }
    Wt[tid] = f2bf(weight[(size_t)k * COUT + co]);
  }
  if (mode >= 2 && tid < NFBF / 4) {
    // thread = (row, lr): reads feats[row][lr + 16*ct], writes 4 adjacent shorts
    int row = tid >> 4, lr = tid & 15;
    const float* fr = feats + ((size_t)row << 6) + lr;
    short4v v = {f2bf(fr[0]), f2bf(fr[16]), f2bf(fr[32]), f2bf(fr[48])};
    *(short4v*)(fbf + ((size_t)row << 6) + lr * 4) = v;
  }
  if (mode == 3) {
    if (tid < 512) l2bf[tid] = f2bf(l2_w[tid]);   // [16 out][32 in]
    if (tid < 256) l3bf[tid] = f2bf(l3_w[tid]);   // [16 out][16 in]
    if (tid < 32) {
      float g0 = 0.f, g1 = 0.f, g2 = 0.f, cc = l1_b[tid];
      const float* wr = l1_w + tid * 48;
#pragma unroll
      for (int m = 0; m < 16; ++m) { g0 += wr[m]; g1 += wr[16 + m]; g2 += wr[32 + m]; }
#pragma unroll
      for (int i = 0; i < 48; ++i) cc -= wr[i] * centers[i];
      Gc4[tid * 4 + 0] = g0; Gc4[tid * 4 + 1] = g1; Gc4[tid * 4 + 2] = g2; Gc4[tid * 4 + 3] = cc;
    }
  }
  if (tid < BATCH * NPTS * 3) out_tail[tid] = opts[tid];
}

// Fused kernel, 512 threads / TWO 32-point tiles per block (2-tile pipeline):
//   tile 0: front-end -> MLP/agg -> s_agg -> GEMM (coalesced Wt, rotating prefetch)
//   tile 1: index row loaded at kernel START; gathers issued BEFORE tile-0's barrier
//           (fly during GEMM-0); GEMM-1 re-reads the SAME per-block Wt slice
//           -> Wt L2 traffic halved (512->256 MB) + tile-1 front-end hidden.
//   G[8] reloaded from L1-resident Gc4 for tile 1 to keep GEMM-0 live set <128 VGPR.
// LDS 66 KB -> 2 blocks/CU.
__global__ __launch_bounds__(512, 4) void conv_kernel(
    const int* __restrict__ indices, const short* __restrict__ fbf,
    const short* __restrict__ Wt, const short* __restrict__ l2bf,
    const short* __restrict__ l3bf, const float* __restrict__ Gc4,
    const float* __restrict__ l2_b, const float* __restrict__ l3_b,
    const float* __restrict__ input_pts, const float* __restrict__ output_pts,
    const float* __restrict__ bias, float* __restrict__ out) {
  __shared__ __align__(16) short s_agg[PTSC * AGG_STRIDE];   // 66048 B

  const int t = threadIdx.x, blk = blockIdx.x;               // 1024 blocks
  // XCD swizzle: batch = blk&7 -> each batch's fbf (1 MB) pinned to one XCD L2
  const int w = ((blk & 7) << 7) | (blk >> 3);
  const int batch = w >> 7, n0 = (w & 127) * 64;
  const int lane = t & 63, wv = t >> 6, quad = lane >> 4, lrow = lane & 15;
  const size_t bbase = (size_t)batch * NPTS;

  // ---- early independent loads: BOTH tiles' neighbor-id rows ----
  const int myid0 = indices[(bbase + n0) * KNN + t];
  const int myid1 = indices[(bbase + n0 + 32) * KNN + t];

  const float* op0 = output_pts + (bbase + n0 + wv * 4 + quad) * 3;
  const float* ip0 = input_pts + (bbase + myid0) * 3;
  const float px0 = ip0[0] - op0[0], py0 = ip0[1] - op0[1], pz0 = ip0[2] - op0[2];

  // per-lane constants: collapsed-L1 rows; W2 A-frag; W3^T B-frag; biases in MFMA C-layout
  f32x4 G[8];
#pragma unroll
  for (int j = 0; j < 8; ++j) G[j] = *(const f32x4*)(Gc4 + (quad * 8 + j) * 4);
  const short8  w2f = *(const short8*)(l2bf + lrow * 32 + quad * 8);
  const short4v w3f = *(const short4v*)(l3bf + lrow * 16 + quad * 4);
  const f32x4 b2f = *(const f32x4*)(l2_b + quad * 4);
  const float b3v = l3_b[lrow];
  const f32x4 b3f = {b3v, b3v, b3v, b3v};      // layer3 swapped: C[row=nbr][col=m] = b3[m]

  // tile-0 feature gathers upfront (ids via in-wave shuffle; latency under h1 VALU)
  short4v ga[4][4];
#pragma unroll
  for (int pp = 0; pp < 4; ++pp)
#pragma unroll
    for (int j = 0; j < 4; ++j) {
      const int idn = __shfl(myid0, pp * 16 + quad * 4 + j);
      ga[pp][j] = *(const short4v*)(fbf + ((bbase + idn) << 6) + lrow * 4);
    }

  // tile-1 relative position (myid1 issued long ago; latency covered)
  const float* op1 = output_pts + (bbase + n0 + 32 + wv * 4 + quad) * 3;
  const float* ip1 = input_pts + (bbase + myid1) * 3;
  const float px1 = ip1[0] - op1[0], py1 = ip1[1] - op1[1], pz1 = ip1[2] - op1[2];

  // ---- MLP + agg for one tile (h1 x4 -> L2 MFMA x4 -> L3-swapped MFMA x4 ->
  //      16 agg MFMAs -> s_agg). Phase-batched across the wave's 4 points. ----
  auto tile_pass = [&](float tpx, float tpy, float tpz, short4v (&gg)[4][4],
                       const f32x4 (&Gr)[8]) {
    short8 h1f[4];
#pragma unroll
    for (int pp = 0; pp < 4; ++pp) {
      const float qx = __shfl(tpx, pp * 16 + lrow);
      const float qy = __shfl(tpy, pp * 16 + lrow);
      const float qz = __shfl(tpz, pp * 16 + lrow);
#pragma unroll
      for (int j = 0; j < 8; ++j) {
        const f32x4 Gx = Gr[j];
        h1f[pp][j] = f2bf(fmaxf(fmaf(Gx[0], qx, fmaf(Gx[1], qy, fmaf(Gx[2], qz, Gx[3]))), 0.f));
      }
    }
    f32x4 h2[4];
#pragma unroll
    for (int pp = 0; pp < 4; ++pp)
      h2[pp] = __builtin_amdgcn_mfma_f32_16x16x32_bf16(w2f, h1f[pp], b2f, 0, 0, 0);
    short4v h2f[4];
#pragma unroll
    for (int pp = 0; pp < 4; ++pp)
#pragma unroll
      for (int r = 0; r < 4; ++r) h2f[pp][r] = f2bf(fmaxf(h2[pp][r], 0.f));
    f32x4 h3[4];
#pragma unroll
    for (int pp = 0; pp < 4; ++pp)
      h3[pp] = __builtin_amdgcn_mfma_f32_16x16x16bf16_1k(h2f[pp], w3f, b3f, 0, 0, 0);
    short4v dfr[4];   // relu + /K fold; this IS the agg B-frag
#pragma unroll
    for (int pp = 0; pp < 4; ++pp)
#pragma unroll
      for (int r = 0; r < 4; ++r) dfr[pp][r] = f2bf(fmaxf(h3[pp][r], 0.f) * 0.0625f);
#pragma unroll
    for (int pp = 0; pp < 4; ++pp) {
      const int pt = wv * 4 + pp;
      const short4v g0 = gg[pp][0], g1 = gg[pp][1], g2 = gg[pp][2], g3 = gg[pp][3];
#pragma unroll
      for (int ct = 0; ct < 4; ++ct) {
        const short4v afr = {g0[ct], g1[ct], g2[ct], g3[ct]};
        const f32x4 dd = __builtin_amdgcn_mfma_f32_16x16x16bf16_1k(
            afr, dfr[pp], (f32x4){0.f, 0.f, 0.f, 0.f}, 0, 0, 0);
        short4v sv;
#pragma unroll
        for (int r = 0; r < 4; ++r) sv[r] = f2bf(dd[r]);
        // slot = ct*256 + m*16 + q*4 + r  (contiguous b64; 4 dw/bank uniform)
        *(short4v*)&s_agg[pt * AGG_STRIDE + ct * 256 + lrow * 16 + quad * 4] = sv;
      }
    }
  };

  // coalesced Wt: wave wv, iter kb -> contiguous 1KB at (wv*32+kb)*1024B;
  // lane (quad,lrow) owns 16B chunk lrow*4+quad.
  const int co = wv * 16 + lrow;
  const short* wp = Wt + wv * 16384 + lrow * 32 + quad * 8;
  const float bi = bias[co];
  const short* a0 = s_agg + lrow * AGG_STRIDE + quad * 8;    // rows 0..15
  const short* a1 = a0 + 16 * AGG_STRIDE;                    // rows 16..31

  // ---- GEMM [32 x 1024] @ [1024 x 128] from s_agg; rotating 4-deep B prefetch.
  //      Bpf[0..3] must be pre-loaded by caller BEFORE the barrier. ----
  auto gemm_out = [&](short8 (&Bpf)[4], int row0) {
    f32x4 acc0 = {0.f, 0.f, 0.f, 0.f};
    f32x4 acc1 = {0.f, 0.f, 0.f, 0.f};
#pragma unroll
    for (int kb = 0; kb < 32; ++kb) {
      const short8 bfr = Bpf[kb & 3];
      if (kb < 28) Bpf[kb & 3] = *(const short8*)(wp + (kb + 4) * 512);
      const short8 av0 = *(const short8*)(a0 + kb * 32);
      const short8 av1 = *(const short8*)(a1 + kb * 32);
      acc0 = __builtin_amdgcn_mfma_f32_16x16x32_bf16(av0, bfr, acc0, 0, 0, 0);
      acc1 = __builtin_amdgcn_mfma_f32_16x16x32_bf16(av1, bfr, acc1, 0, 0, 0);
    }
#pragma unroll
    for (int r = 0; r < 4; ++r) {
      const int p0 = quad * 4 + r;               // D: row=quad*4+reg, col=lane&15
      out[(bbase + row0 + p0) * COUT + co] = acc0[r] + bi;
      out[(bbase + row0 + 16 + p0) * COUT + co] = acc1[r] + bi;
    }
  };

  // ================= tile 0 =================
  tile_pass(px0, py0, pz0, ga, G);

  // tile-1 gathers issued NOW: global loads stay in flight across the barrier
  // and GEMM-0 (lgkm-only drain below does not touch vmcnt)
  short4v gb[4][4];
#pragma unroll
  for (int pp = 0; pp < 4; ++pp)
#pragma unroll
    for (int j = 0; j < 4; ++j) {
      const int idn = __shfl(myid1, pp * 16 + quad * 4 + j);
      gb[pp][j] = *(const short4v*)(fbf + ((bbase + idn) << 6) + lrow * 4);
    }

  short8 Bpf[4];
#pragma unroll
  for (int i = 0; i < 4; ++i) Bpf[i] = *(const short8*)(wp + i * 512);

  asm volatile("s_waitcnt lgkmcnt(0)" ::: "memory");   // s_agg writes + bpermutes done
  __builtin_amdgcn_s_barrier();
  asm volatile("" ::: "memory");                       // fence: no ds_read hoist

  gemm_out(Bpf, n0);

  __builtin_amdgcn_s_barrier();                        // all waves done reading s_agg
  asm volatile("" ::: "memory");

  // ================= tile 1 =================
  f32x4 G2[8];                                         // reload (L1-resident Gc4)
#pragma unroll
  for (int j = 0; j < 8; ++j) G2[j] = *(const f32x4*)(Gc4 + (quad * 8 + j) * 4);

  tile_pass(px1, py1, pz1, gb, G2);

#pragma unroll
  for (int i = 0; i < 4; ++i) Bpf[i] = *(const short8*)(wp + i * 512);  // L2-hit

  asm volatile("s_waitcnt lgkmcnt(0)" ::: "memory");
  __builtin_amdgcn_s_barrier();
  asm volatile("" ::: "memory");

  gemm_out(Bpf, n0 + 32);
}

// ---------------- fallback monolithic kernel, small workspace ----------------
// (modes 0-2 only; uses the old co-major Wt layout which prep still writes there)
template <int MODE>
__global__ __launch_bounds__(256, 3) void ptconv_mono(
    const float* __restrict__ features, const float* __restrict__ input_pts,
    const float* __restrict__ output_pts, const int* __restrict__ indices,
    const float* __restrict__ centers, const float* __restrict__ weight,
    const float* __restrict__ bias,
    const float* __restrict__ l1_w, const float* __restrict__ l1_b,
    const float* __restrict__ l2_w, const float* __restrict__ l2_b,
    const float* __restrict__ l3_w, const float* __restrict__ l3_b,
    const short* __restrict__ Wt, const short* __restrict__ fbf,
    float* __restrict__ out) {
  __shared__ __align__(16) short s_dT[MD * DT_STR];
  __shared__ __align__(16) short s_agg[PTS * AGG_STRIDE];
  __shared__ __align__(16) int   s_idx[PTS * KNN];

  const int t = threadIdx.x;
  const int blk = blockIdx.x;
  const int batch = blk >> 9;
  const int n0 = (blk & 511) * PTS;
  const int lane = t & 63;
  const int wv = t >> 6;
  const int quad = lane >> 4;
  const int lrow = lane & 15;

  s_idx[t] = indices[((size_t)batch * NPTS + n0) * KNN + t];
  {
    const int pt = t >> 4;
    const int id = s_idx[t];
    const float* op = &output_pts[((size_t)batch * NPTS + n0 + pt) * 3];
    const float* ip = &input_pts[((size_t)batch * NPTS + id) * 3];
    const float px = ip[0] - op[0], py = ip[1] - op[1], pz = ip[2] - op[2];
    f32x2 dv[24];
    {
      const f32x2 px2 = {px, px}, py2 = {py, py}, pz2 = {pz, pz};
      const f32x2* cx = (const f32x2*)centers;
      const f32x2* cy = (const f32x2*)(centers + 16);
      const f32x2* cz = (const f32x2*)(centers + 32);
#pragma unroll
      for (int i = 0; i < 8; ++i) {
        dv[i] = px2 - cx[i]; dv[8 + i] = py2 - cy[i]; dv[16 + i] = pz2 - cz[i];
      }
    }
    float h1[32];
#pragma unroll
    for (int o = 0; o < 32; ++o) {
      const f32x2* wr = (const f32x2*)(l1_w + o * 48);
      f32x2 acc = {0.f, 0.f};
#pragma unroll
      for (int i = 0; i < 24; ++i) acc += dv[i] * wr[i];
      h1[o] = fmaxf(acc[0] + acc[1] + l1_b[o], 0.f);
    }
    f32x2 h1v[16];
#pragma unroll
    for (int i = 0; i < 16; ++i) h1v[i] = (f32x2){h1[2 * i], h1[2 * i + 1]};
    float h2[16];
#pragma unroll
    for (int o = 0; o < 16; ++o) {
      const f32x2* wr = (const f32x2*)(l2_w + o * 32);
      f32x2 acc = {0.f, 0.f};
#pragma unroll
      for (int i = 0; i < 16; ++i) acc += h1v[i] * wr[i];
      h2[o] = fmaxf(acc[0] + acc[1] + l2_b[o], 0.f);
    }
    f32x2 h2v[8];
#pragma unroll
    for (int i = 0; i < 8; ++i) h2v[i] = (f32x2){h2[2 * i], h2[2 * i + 1]};
#pragma unroll
    for (int o = 0; o < 16; ++o) {
      const f32x2* wr = (const f32x2*)(l3_w + o * 16);
      f32x2 acc = {0.f, 0.f};
#pragma unroll
      for (int i = 0; i < 8; ++i) acc += h2v[i] * wr[i];
      s_dT[o * DT_STR + t] = f2bf(fmaxf(acc[0] + acc[1] + l3_b[o], 0.f));
    }
  }
  __syncthreads();
  {
#pragma unroll
    for (int pp = 0; pp < 4; ++pp) {
      const int pt = wv * 4 + pp;
      const short4v bfrag = *(const short4v*)&s_dT[lrow * DT_STR + pt * 16 + quad * 4];
      const int4 idx4 = *(const int4*)&s_idx[pt * 16 + quad * 4];
#pragma unroll
      for (int ct = 0; ct < 4; ++ct) {
        short4v afr;
#pragma unroll
        for (int j = 0; j < 4; ++j) {
          const int id = ((const int*)&idx4)[j];
          const size_t base = ((size_t)batch * NPTS + id) * CIN;
          if (MODE >= 2) afr[j] = fbf[base + lrow * 4 + ct];      // interleaved layout
          else           afr[j] = f2bf(features[base + ct * 16 + lrow]);
        }
        f32x4 dd = __builtin_amdgcn_mfma_f32_16x16x16bf16_1k(
            afr, bfrag, (f32x4){0.f, 0.f, 0.f, 0.f}, 0, 0, 0);
#pragma unroll
        for (int r = 0; r < 4; ++r) {
          const int rr = (r + quad) & 3;
          const int c = ct * 16 + quad * 4 + rr;
          s_agg[pt * AGG_STRIDE + c * 16 + lrow] = f2bf(dd[rr]);
        }
      }
    }
  }
  __syncthreads();
  {
    f32x4 acc0 = {0.f, 0.f, 0.f, 0.f};
    f32x4 acc1 = {0.f, 0.f, 0.f, 0.f};
    const int co0 = wv * 32 + lrow;
    const int co1 = co0 + 16;
    const short* arow = s_agg + lrow * AGG_STRIDE + quad * 8;
#pragma unroll 4
    for (int kb = 0; kb < 32; ++kb) {
      const short8 a = *(const short8*)(arow + kb * 32);
      short8 b0, b1;
      if (MODE >= 1) {
        b0 = *(const short8*)(Wt + (size_t)co0 * 1024 + kb * 32 + quad * 8);
        b1 = *(const short8*)(Wt + (size_t)co1 * 1024 + kb * 32 + quad * 8);
      } else {
#pragma unroll
        for (int j = 0; j < 8; ++j) {
          const int kk = kb * 32 + quad * 8 + j;
          b0[j] = f2bf(weight[(size_t)kk * COUT + co0]);
          b1[j] = f2bf(weight[(size_t)kk * COUT + co1]);
        }
      }
      acc0 = __builtin_amdgcn_mfma_f32_16x16x32_bf16(a, b0, acc0, 0, 0, 0);
      acc1 = __builtin_amdgcn_mfma_f32_16x16x32_bf16(a, b1, acc1, 0, 0, 0);
    }
    const float bi0 = bias[co0], bi1 = bias[co1];
#pragma unroll
    for (int r = 0; r < 4; ++r) {
      const int pt = quad * 4 + r;
      const size_t rowo = ((size_t)batch * NPTS + n0 + pt) * COUT;
      out[rowo + co0] = acc0[r] * 0.0625f + bi0;
      out[rowo + co1] = acc1[r] * 0.0625f + bi1;
    }
  }
}

extern "C" void kernel_launch(void* const* d_in, const int* in_sizes, int n_in,
                              void* d_out, int out_size, void* d_ws, size_t ws_size,
                              hipStream_t stream) {
  const float* features   = (const float*)d_in[0];
  const float* input_pts  = (const float*)d_in[1];
  const float* output_pts = (const float*)d_in[2];
  const int*   indices    = (const int*)d_in[3];
  const float* centers    = (const float*)d_in[4];
  const float* weight     = (const float*)d_in[5];
  const float* bias       = (const float*)d_in[6];
  const float* l1_w       = (const float*)d_in[7];
  const float* l1_b       = (const float*)d_in[8];
  const float* l2_w       = (const float*)d_in[9];
  const float* l2_b       = (const float*)d_in[10];
  const float* l3_w       = (const float*)d_in[11];
  const float* l3_b       = (const float*)d_in[12];
  float* out = (float*)d_out;

  short* Wt   = (short*)d_ws;
  short* fbf  = Wt + NWT;
  short* l2bf = fbf + NFBF;
  short* l3bf = l2bf + 512;
  float* Gc4  = (float*)(l3bf + 256);       // 128 floats (base 16B aligned)
  const size_t need3 = (size_t)(NWT + NFBF + 512 + 256) * 2 + 512;

  int mode = 0;
  if (ws_size >= need3) mode = 3;
  else if (ws_size >= (size_t)(NWT + NFBF) * 2) mode = 2;
  else if (ws_size >= (size_t)NWT * 2) mode = 1;

  float* out_tail = out + (size_t)BATCH * NPTS * COUT;
  const int prep_elems = (mode >= 2) ? (NFBF / 4) : BATCH * NPTS * 3;
  prep_kernel<<<(prep_elems + 255) / 256, 256, 0, stream>>>(
      weight, output_pts, features, centers, l1_w, l1_b, l2_w, l3_w,
      Wt, fbf, l2bf, l3bf, Gc4, out_tail, mode);

  if (mode == 3) {
    conv_kernel<<<NPTS_G / 64, 512, 0, stream>>>(
        indices, fbf, Wt, l2bf, l3bf, Gc4, l2_b, l3_b, input_pts, output_pts, bias, out);
  } else if (mode == 2) {
    ptconv_mono<2><<<NPTS_G / PTS, 256, 0, stream>>>(features, input_pts, output_pts, indices,
        centers, weight, bias, l1_w, l1_b, l2_w, l2_b, l3_w, l3_b, Wt, fbf, out);
  } else if (mode == 1) {
    ptconv_mono<1><<<NPTS_G / PTS, 256, 0, stream>>>(features, input_pts, output_pts, indices,
        centers, weight, bias, l1_w, l1_b, l2_w, l2_b, l3_w, l3_b, Wt, fbf, out);
  } else {
    ptconv_mono<0><<<NPTS_G / PTS, 256, 0, stream>>>(features, input_pts, output_pts, indices,
        centers, weight, bias, l1_w, l1_b, l2_w, l2_b, l3_w, l3_b, Wt, fbf, out);
  }
}

// Round 12
// 144.537 us; speedup vs baseline: 1.0842x; 1.0842x over previous
//
#include <hip/hip_runtime.h>

// PtConv: B=8, N=8192, C_IN=64, C_OUT=128, K=16, M=16, DIM=3
#define BATCH 8
#define NPTS  8192
#define CIN   64
#define COUT  128
#define KNN   16
#define MD    16
#define PTS   16            // mono fallback points/block
#define PTSC  32            // conv points/block (512 threads, 8 waves)
#define DT_STR 264          // mono fallback only
#define AGG_STRIDE 1032     // s_agg per-point stride (shorts); 516 dw == 4 mod 32

#define NWT    (COUT * CIN * MD)          // 131072 bf16
#define NFBF   (BATCH * NPTS * CIN)       // 4194304 bf16
#define NPTS_G (BATCH * NPTS)             // 65536

typedef __attribute__((ext_vector_type(8))) short short8;
typedef __attribute__((ext_vector_type(4))) short short4v;
typedef __attribute__((ext_vector_type(4))) float f32x4;
typedef __attribute__((ext_vector_type(2))) float f32x2;

// RNE f32->bf16 bit-hack (round-4-verified). NOTE r8: the native __bf16 cast
// REGRESSED (83.5->97.3us) despite fewer VALU ops — these independent int ops
// overlap stall cycles; do not "optimize" this again.
__device__ __forceinline__ short f2bf(float f) {
  unsigned u = __float_as_uint(f);
  u = (u + 0x7fffu + ((u >> 16) & 1u)) >> 16;   // RNE
  return (short)u;
}

// prep (mode 3): Wt = bf16 W^T in WAVE-COALESCED layout: 16B chunk
//   L = ((wv*32 + kb)*16 + lrow)*4 + quad   holds  Wt_old[co=wv*16+lrow][o=kb*32+quad*8..+8]
// so a conv wave's per-kb B-fragment load is one contiguous 1KB line (r9: -30% conv).
// k-slot permutation o->k matches conv s_agg layout. fbf = channel-interleaved bf16
// features; l2bf/l3bf = bf16 MLP weights; Gc4 = collapsed layer-1; out tail = opts copy.
__global__ __launch_bounds__(256) void prep_kernel(
    const float* __restrict__ weight, const float* __restrict__ opts,
    const float* __restrict__ feats, const float* __restrict__ centers,
    const float* __restrict__ l1_w, const float* __restrict__ l1_b,
    const float* __restrict__ l2_w, const float* __restrict__ l3_w,
    short* __restrict__ Wt, short* __restrict__ fbf,
    short* __restrict__ l2bf, short* __restrict__ l3bf, float* __restrict__ Gc4,
    float* __restrict__ out_tail, int mode) {
  int tid = blockIdx.x * 256 + threadIdx.x;
  if (mode >= 1 && tid < NWT) {
    int co, o;
    if (mode == 3) {
      // decode coalesced slot: tid = (((wv*32+kb)*16+lrow)*4+quad)*8 + j
      int j = tid & 7, quad = (tid >> 3) & 3, lrow = (tid >> 5) & 15;
      int kb = (tid >> 9) & 31, wv = tid >> 14;
      co = wv * 16 + lrow;
      o = kb * 32 + quad * 8 + j;
    } else {
      co = tid >> 10;
      o = tid & 1023;
    }
    int k;
    if (mode == 3) {  // slot o = ct*256 + m*16 + q*4 + r  holds  k = ct*256 + q*64 + r*16 + m
      int r = o & 3, q = (o >> 2) & 3, m = (o >> 4) & 15, ct = o >> 8;
      k = ct * 256 + q * 64 + r * 16 + m;
    } else {
      k = o;
    }
    Wt[tid] = f2bf(weight[(size_t)k * COUT + co]);
  }
  if (mode >= 2 && tid < NFBF / 4) {
    // thread = (row, lr): reads feats[row][lr + 16*ct], writes 4 adjacent shorts
    int row = tid >> 4, lr = tid & 15;
    const float* fr = feats + ((size_t)row << 6) + lr;
    short4v v = {f2bf(fr[0]), f2bf(fr[16]), f2bf(fr[32]), f2bf(fr[48])};
    *(short4v*)(fbf + ((size_t)row << 6) + lr * 4) = v;
  }
  if (mode == 3) {
    if (tid < 512) l2bf[tid] = f2bf(l2_w[tid]);   // [16 out][32 in]
    if (tid < 256) l3bf[tid] = f2bf(l3_w[tid]);   // [16 out][16 in]
    if (tid < 32) {
      float g0 = 0.f, g1 = 0.f, g2 = 0.f, cc = l1_b[tid];
      const float* wr = l1_w + tid * 48;
#pragma unroll
      for (int m = 0; m < 16; ++m) { g0 += wr[m]; g1 += wr[16 + m]; g2 += wr[32 + m]; }
#pragma unroll
      for (int i = 0; i < 48; ++i) cc -= wr[i] * centers[i];
      Gc4[tid * 4 + 0] = g0; Gc4[tid * 4 + 1] = g1; Gc4[tid * 4 + 2] = g2; Gc4[tid * 4 + 3] = cc;
    }
  }
  if (tid < BATCH * NPTS * 3) out_tail[tid] = opts[tid];
}

// Fused kernel, 512 threads / 32 points per block (round-9 structure = session best):
//   phase 0-2: per-neighbor MLP, phase-batched across the wave's 4 points (4-wide
//              MFMA/VALU ILP); layer-3 operand-swapped so its D IS the agg B-frag.
//   barrier:   lgkmcnt(0)-only + raw s_barrier -> pre-issued Wt prefetch loads
//              stay in flight across the barrier.
//   phase 3:   output GEMM [32 x 1024] @ [1024 x 128]; COALESCED Wt B-loads
//              (1KB contiguous per wave per kb); setprio(1) during GEMM (T5):
//              the 2 resident blocks/CU are unsynchronized, so GEMM-phase waves
//              get priority over front-end-phase waves of the other block.
// LDS 66 KB -> 2 blocks/CU -> 16 waves/CU.
// r11 lesson: do NOT carry next-tile gather registers across the GEMM —
// 128B/thread of live state spilled to scratch (FETCH 8->40MB, WRITE 33->86MB).
__global__ __launch_bounds__(512, 4) void conv_kernel(
    const int* __restrict__ indices, const short* __restrict__ fbf,
    const short* __restrict__ Wt, const short* __restrict__ l2bf,
    const short* __restrict__ l3bf, const float* __restrict__ Gc4,
    const float* __restrict__ l2_b, const float* __restrict__ l3_b,
    const float* __restrict__ input_pts, const float* __restrict__ output_pts,
    const float* __restrict__ bias, float* __restrict__ out) {
  __shared__ __align__(16) short s_agg[PTSC * AGG_STRIDE];   // 66048 B

  const int t = threadIdx.x, blk = blockIdx.x;               // 2048 blocks
  // XCD swizzle: batch = blk&7 -> each batch's fbf (1 MB) pinned to one XCD L2
  const int w = ((blk & 7) << 8) | (blk >> 3);
  const int batch = w >> 8, n0 = (w & 255) * PTSC;
  const int lane = t & 63, wv = t >> 6, quad = lane >> 4, lrow = lane & 15;
  const size_t bbase = (size_t)batch * NPTS;

  // thread t <-> (pt = wv*4+quad, nbr = lrow): own neighbor id + relative position
  const int myid = indices[(bbase + n0) * KNN + t];
  const float* op = output_pts + (bbase + n0 + wv * 4 + quad) * 3;
  const float* ip = input_pts + (bbase + myid) * 3;
  const float px = ip[0] - op[0], py = ip[1] - op[1], pz = ip[2] - op[2];

  // per-lane constants: collapsed-L1 rows; W2 A-frag; W3^T B-frag; biases in MFMA C-layout
  f32x4 G[8];
#pragma unroll
  for (int j = 0; j < 8; ++j) G[j] = *(const f32x4*)(Gc4 + (quad * 8 + j) * 4);
  const short8  w2f = *(const short8*)(l2bf + lrow * 32 + quad * 8);
  const short4v w3f = *(const short4v*)(l3bf + lrow * 16 + quad * 4);
  const f32x4 b2f = *(const f32x4*)(l2_b + quad * 4);
  const float b3v = l3_b[lrow];
  const f32x4 b3f = {b3v, b3v, b3v, b3v};      // layer3 swapped: C[row=nbr][col=m] = b3[m]

  // all 16 feature gathers upfront (ids via in-wave shuffle of myid; 16 L2 loads
  // in flight, latency hidden under the h1 VALU block below)
  short4v g[4][4];
#pragma unroll
  for (int pp = 0; pp < 4; ++pp)
#pragma unroll
    for (int j = 0; j < 4; ++j) {
      const int idn = __shfl(myid, pp * 16 + quad * 4 + j);
      g[pp][j] = *(const short4v*)(fbf + ((bbase + idn) << 6) + lrow * 4);
    }

  // ---- h1 for all 4 points (pure VALU; B-frag layout [k=q*8+j][nbr=lrow]) ----
  short8 h1f[4];
#pragma unroll
  for (int pp = 0; pp < 4; ++pp) {
    const float qx = __shfl(px, pp * 16 + lrow);
    const float qy = __shfl(py, pp * 16 + lrow);
    const float qz = __shfl(pz, pp * 16 + lrow);
#pragma unroll
    for (int j = 0; j < 8; ++j) {
      const f32x4 Gx = G[j];
      h1f[pp][j] = f2bf(fmaxf(fmaf(Gx[0], qx, fmaf(Gx[1], qy, fmaf(Gx[2], qz, Gx[3]))), 0.f));
    }
  }

  // ---- layer2 x4 (independent MFMAs): D[h2feat=q*4+r][nbr=lrow] = W2@h1 + b2 ----
  f32x4 h2[4];
#pragma unroll
  for (int pp = 0; pp < 4; ++pp)
    h2[pp] = __builtin_amdgcn_mfma_f32_16x16x32_bf16(w2f, h1f[pp], b2f, 0, 0, 0);
  short4v h2f[4];
#pragma unroll
  for (int pp = 0; pp < 4; ++pp)
#pragma unroll
    for (int r = 0; r < 4; ++r) h2f[pp][r] = f2bf(fmaxf(h2[pp][r], 0.f));

  // ---- layer3 x4 SWAPPED: D = H2^T @ W3^T + b3 -> D[nbr=q*4+r][m=lrow] ----
  f32x4 h3[4];
#pragma unroll
  for (int pp = 0; pp < 4; ++pp)
    h3[pp] = __builtin_amdgcn_mfma_f32_16x16x16bf16_1k(h2f[pp], w3f, b3f, 0, 0, 0);
  short4v dfr[4];   // relu + /K fold; this IS the agg B-frag
#pragma unroll
  for (int pp = 0; pp < 4; ++pp)
#pragma unroll
    for (int r = 0; r < 4; ++r) dfr[pp][r] = f2bf(fmaxf(h3[pp][r], 0.f) * 0.0625f);

  // ---- agg: 16 independent MFMAs -> s_agg ----
#pragma unroll
  for (int pp = 0; pp < 4; ++pp) {
    const int pt = wv * 4 + pp;
    const short4v g0 = g[pp][0], g1 = g[pp][1], g2 = g[pp][2], g3 = g[pp][3];
#pragma unroll
    for (int ct = 0; ct < 4; ++ct) {
      const short4v afr = {g0[ct], g1[ct], g2[ct], g3[ct]};
      const f32x4 dd = __builtin_amdgcn_mfma_f32_16x16x16bf16_1k(
          afr, dfr[pp], (f32x4){0.f, 0.f, 0.f, 0.f}, 0, 0, 0);
      short4v sv;
#pragma unroll
      for (int r = 0; r < 4; ++r) sv[r] = f2bf(dd[r]);
      // slot = ct*256 + m*16 + q*4 + r  (contiguous b64; 4 dw/bank uniform)
      *(short4v*)&s_agg[pt * AGG_STRIDE + ct * 256 + lrow * 16 + quad * 4] = sv;
    }
  }

  // ---- pre-barrier Wt prefetch (stays in flight across the barrier: we drain
  //      only lgkmcnt for the ds_writes, NOT vmcnt like __syncthreads would) ----
  // coalesced layout: wave wv, iter kb -> contiguous 1KB at (wv*32+kb)*1024B;
  // lane (quad,lrow) owns 16B chunk lrow*4+quad.
  const int co = wv * 16 + lrow;
  const short* wp = Wt + wv * 16384 + lrow * 32 + quad * 8;
  short8 Bpf[4];
#pragma unroll
  for (int i = 0; i < 4; ++i) Bpf[i] = *(const short8*)(wp + i * 512);

  asm volatile("s_waitcnt lgkmcnt(0)" ::: "memory");   // s_agg writes visible
  __builtin_amdgcn_s_barrier();
  asm volatile("" ::: "memory");                       // fence: no ds_read hoist

  // ---- phase 3: MFMA GEMM [32 x 1024] @ [1024 x 128]; wave = 16 cols x 32 rows;
  //      fully unrolled, rotating 4-deep B prefetch (static indices post-unroll).
  //      setprio(1): favor GEMM-phase waves over the other block's front-end (T5). ----
  f32x4 acc0 = {0.f, 0.f, 0.f, 0.f};
  f32x4 acc1 = {0.f, 0.f, 0.f, 0.f};
  const short* a0 = s_agg + lrow * AGG_STRIDE + quad * 8;    // rows 0..15
  const short* a1 = a0 + 16 * AGG_STRIDE;                    // rows 16..31
  __builtin_amdgcn_s_setprio(1);
#pragma unroll
  for (int kb = 0; kb < 32; ++kb) {
    const short8 bfr = Bpf[kb & 3];
    if (kb < 28) Bpf[kb & 3] = *(const short8*)(wp + (kb + 4) * 512);
    const short8 av0 = *(const short8*)(a0 + kb * 32);
    const short8 av1 = *(const short8*)(a1 + kb * 32);
    acc0 = __builtin_amdgcn_mfma_f32_16x16x32_bf16(av0, bfr, acc0, 0, 0, 0);
    acc1 = __builtin_amdgcn_mfma_f32_16x16x32_bf16(av1, bfr, acc1, 0, 0, 0);
  }
  __builtin_amdgcn_s_setprio(0);
  const float bi = bias[co];
#pragma unroll
  for (int r = 0; r < 4; ++r) {
    const int p0 = quad * 4 + r;                 // D: row=quad*4+reg, col=lane&15
    out[(bbase + n0 + p0) * COUT + co] = acc0[r] + bi;
    out[(bbase + n0 + 16 + p0) * COUT + co] = acc1[r] + bi;
  }
}

// ---------------- fallback monolithic kernel, small workspace ----------------
// (modes 0-2 only; uses the old co-major Wt layout which prep still writes there)
template <int MODE>
__global__ __launch_bounds__(256, 3) void ptconv_mono(
    const float* __restrict__ features, const float* __restrict__ input_pts,
    const float* __restrict__ output_pts, const int* __restrict__ indices,
    const float* __restrict__ centers, const float* __restrict__ weight,
    const float* __restrict__ bias,
    const float* __restrict__ l1_w, const float* __restrict__ l1_b,
    const float* __restrict__ l2_w, const float* __restrict__ l2_b,
    const float* __restrict__ l3_w, const float* __restrict__ l3_b,
    const short* __restrict__ Wt, const short* __restrict__ fbf,
    float* __restrict__ out) {
  __shared__ __align__(16) short s_dT[MD * DT_STR];
  __shared__ __align__(16) short s_agg[PTS * AGG_STRIDE];
  __shared__ __align__(16) int   s_idx[PTS * KNN];

  const int t = threadIdx.x;
  const int blk = blockIdx.x;
  const int batch = blk >> 9;
  const int n0 = (blk & 511) * PTS;
  const int lane = t & 63;
  const int wv = t >> 6;
  const int quad = lane >> 4;
  const int lrow = lane & 15;

  s_idx[t] = indices[((size_t)batch * NPTS + n0) * KNN + t];
  {
    const int pt = t >> 4;
    const int id = s_idx[t];
    const float* op = &output_pts[((size_t)batch * NPTS + n0 + pt) * 3];
    const float* ip = &input_pts[((size_t)batch * NPTS + id) * 3];
    const float px = ip[0] - op[0], py = ip[1] - op[1], pz = ip[2] - op[2];
    f32x2 dv[24];
    {
      const f32x2 px2 = {px, px}, py2 = {py, py}, pz2 = {pz, pz};
      const f32x2* cx = (const f32x2*)centers;
      const f32x2* cy = (const f32x2*)(centers + 16);
      const f32x2* cz = (const f32x2*)(centers + 32);
#pragma unroll
      for (int i = 0; i < 8; ++i) {
        dv[i] = px2 - cx[i]; dv[8 + i] = py2 - cy[i]; dv[16 + i] = pz2 - cz[i];
      }
    }
    float h1[32];
#pragma unroll
    for (int o = 0; o < 32; ++o) {
      const f32x2* wr = (const f32x2*)(l1_w + o * 48);
      f32x2 acc = {0.f, 0.f};
#pragma unroll
      for (int i = 0; i < 24; ++i) acc += dv[i] * wr[i];
      h1[o] = fmaxf(acc[0] + acc[1] + l1_b[o], 0.f);
    }
    f32x2 h1v[16];
#pragma unroll
    for (int i = 0; i < 16; ++i) h1v[i] = (f32x2){h1[2 * i], h1[2 * i + 1]};
    float h2[16];
#pragma unroll
    for (int o = 0; o < 16; ++o) {
      const f32x2* wr = (const f32x2*)(l2_w + o * 32);
      f32x2 acc = {0.f, 0.f};
#pragma unroll
      for (int i = 0; i < 16; ++i) acc += h1v[i] * wr[i];
      h2[o] = fmaxf(acc[0] + acc[1] + l2_b[o], 0.f);
    }
    f32x2 h2v[8];
#pragma unroll
    for (int i = 0; i < 8; ++i) h2v[i] = (f32x2){h2[2 * i], h2[2 * i + 1]};
#pragma unroll
    for (int o = 0; o < 16; ++o) {
      const f32x2* wr = (const f32x2*)(l3_w + o * 16);
      f32x2 acc = {0.f, 0.f};
#pragma unroll
      for (int i = 0; i < 8; ++i) acc += h2v[i] * wr[i];
      s_dT[o * DT_STR + t] = f2bf(fmaxf(acc[0] + acc[1] + l3_b[o], 0.f));
    }
  }
  __syncthreads();
  {
#pragma unroll
    for (int pp = 0; pp < 4; ++pp) {
      const int pt = wv * 4 + pp;
      const short4v bfrag = *(const short4v*)&s_dT[lrow * DT_STR + pt * 16 + quad * 4];
      const int4 idx4 = *(const int4*)&s_idx[pt * 16 + quad * 4];
#pragma unroll
      for (int ct = 0; ct < 4; ++ct) {
        short4v afr;
#pragma unroll
        for (int j = 0; j < 4; ++j) {
          const int id = ((const int*)&idx4)[j];
          const size_t base = ((size_t)batch * NPTS + id) * CIN;
          if (MODE >= 2) afr[j] = fbf[base + lrow * 4 + ct];      // interleaved layout
          else           afr[j] = f2bf(features[base + ct * 16 + lrow]);
        }
        f32x4 dd = __builtin_amdgcn_mfma_f32_16x16x16bf16_1k(
            afr, bfrag, (f32x4){0.f, 0.f, 0.f, 0.f}, 0, 0, 0);
#pragma unroll
        for (int r = 0; r < 4; ++r) {
          const int rr = (r + quad) & 3;
          const int c = ct * 16 + quad * 4 + rr;
          s_agg[pt * AGG_STRIDE + c * 16 + lrow] = f2bf(dd[rr]);
        }
      }
    }
  }
  __syncthreads();
  {
    f32x4 acc0 = {0.f, 0.f, 0.f, 0.f};
    f32x4 acc1 = {0.f, 0.f, 0.f, 0.f};
    const int co0 = wv * 32 + lrow;
    const int co1 = co0 + 16;
    const short* arow = s_agg + lrow * AGG_STRIDE + quad * 8;
#pragma unroll 4
    for (int kb = 0; kb < 32; ++kb) {
      const short8 a = *(const short8*)(arow + kb * 32);
      short8 b0, b1;
      if (MODE >= 1) {
        b0 = *(const short8*)(Wt + (size_t)co0 * 1024 + kb * 32 + quad * 8);
        b1 = *(const short8*)(Wt + (size_t)co1 * 1024 + kb * 32 + quad * 8);
      } else {
#pragma unroll
        for (int j = 0; j < 8; ++j) {
          const int kk = kb * 32 + quad * 8 + j;
          b0[j] = f2bf(weight[(size_t)kk * COUT + co0]);
          b1[j] = f2bf(weight[(size_t)kk * COUT + co1]);
        }
      }
      acc0 = __builtin_amdgcn_mfma_f32_16x16x32_bf16(a, b0, acc0, 0, 0, 0);
      acc1 = __builtin_amdgcn_mfma_f32_16x16x32_bf16(a, b1, acc1, 0, 0, 0);
    }
    const float bi0 = bias[co0], bi1 = bias[co1];
#pragma unroll
    for (int r = 0; r < 4; ++r) {
      const int pt = quad * 4 + r;
      const size_t rowo = ((size_t)batch * NPTS + n0 + pt) * COUT;
      out[rowo + co0] = acc0[r] * 0.0625f + bi0;
      out[rowo + co1] = acc1[r] * 0.0625f + bi1;
    }
  }
}

extern "C" void kernel_launch(void* const* d_in, const int* in_sizes, int n_in,
                              void* d_out, int out_size, void* d_ws, size_t ws_size,
                              hipStream_t stream) {
  const float* features   = (const float*)d_in[0];
  const float* input_pts  = (const float*)d_in[1];
  const float* output_pts = (const float*)d_in[2];
  const int*   indices    = (const int*)d_in[3];
  const float* centers    = (const float*)d_in[4];
  const float* weight     = (const float*)d_in[5];
  const float* bias       = (const float*)d_in[6];
  const float* l1_w       = (const float*)d_in[7];
  const float* l1_b       = (const float*)d_in[8];
  const float* l2_w       = (const float*)d_in[9];
  const float* l2_b       = (const float*)d_in[10];
  const float* l3_w       = (const float*)d_in[11];
  const float* l3_b       = (const float*)d_in[12];
  float* out = (float*)d_out;

  short* Wt   = (short*)d_ws;
  short* fbf  = Wt + NWT;
  short* l2bf = fbf + NFBF;
  short* l3bf = l2bf + 512;
  float* Gc4  = (float*)(l3bf + 256);       // 128 floats (base 16B aligned)
  const size_t need3 = (size_t)(NWT + NFBF + 512 + 256) * 2 + 512;

  int mode = 0;
  if (ws_size >= need3) mode = 3;
  else if (ws_size >= (size_t)(NWT + NFBF) * 2) mode = 2;
  else if (ws_size >= (size_t)NWT * 2) mode = 1;

  float* out_tail = out + (size_t)BATCH * NPTS * COUT;
  const int prep_elems = (mode >= 2) ? (NFBF / 4) : BATCH * NPTS * 3;
  prep_kernel<<<(prep_elems + 255) / 256, 256, 0, stream>>>(
      weight, output_pts, features, centers, l1_w, l1_b, l2_w, l3_w,
      Wt, fbf, l2bf, l3bf, Gc4, out_tail, mode);

  if (mode == 3) {
    conv_kernel<<<NPTS_G / PTSC, 512, 0, stream>>>(
        indices, fbf, Wt, l2bf, l3bf, Gc4, l2_b, l3_b, input_pts, output_pts, bias, out);
  } else if (mode == 2) {
    ptconv_mono<2><<<NPTS_G / PTS, 256, 0, stream>>>(features, input_pts, output_pts, indices,
        centers, weight, bias, l1_w, l1_b, l2_w, l2_b, l3_w, l3_b, Wt, fbf, out);
  } else if (mode == 1) {
    ptconv_mono<1><<<NPTS_G / PTS, 256, 0, stream>>>(features, input_pts, output_pts, indices,
        centers, weight, bias, l1_w, l1_b, l2_w, l2_b, l3_w, l3_b, Wt, fbf, out);
  } else {
    ptconv_mono<0><<<NPTS_G / PTS, 256, 0, stream>>>(features, input_pts, output_pts, indices,
        centers, weight, bias, l1_w, l1_b, l2_w, l2_b, l3_w, l3_b, Wt, fbf, out);
  }
}

// Round 13
// 135.948 us; speedup vs baseline: 1.1527x; 1.0632x over previous
//
#include <hip/hip_runtime.h>

// PtConv: B=8, N=8192, C_IN=64, C_OUT=128, K=16, M=16, DIM=3
#define BATCH 8
#define NPTS  8192
#define CIN   64
#define COUT  128
#define KNN   16
#define MD    16
#define PTS   16            // mono fallback points/block
#define PTSC  32            // conv points/block (512 threads, 8 waves)
#define DT_STR 264          // mono fallback only
#define AGG_STRIDE 1032     // s_agg per-point stride (shorts); 516 dw == 4 mod 32

#define NWT    (COUT * CIN * MD)          // 131072 bf16
#define NFBF   (BATCH * NPTS * CIN)       // 4194304 bf16
#define NPTS_G (BATCH * NPTS)             // 65536

typedef __attribute__((ext_vector_type(8))) short short8;
typedef __attribute__((ext_vector_type(4))) short short4v;
typedef __attribute__((ext_vector_type(16))) float f32x16;
typedef __attribute__((ext_vector_type(4))) float f32x4;
typedef __attribute__((ext_vector_type(2))) float f32x2;

// RNE f32->bf16 bit-hack (round-4-verified). NOTE r8: the native __bf16 cast
// REGRESSED (83.5->97.3us) despite fewer VALU ops — these independent int ops
// overlap stall cycles; do not "optimize" this again.
__device__ __forceinline__ short f2bf(float f) {
  unsigned u = __float_as_uint(f);
  u = (u + 0x7fffu + ((u >> 16) & 1u)) >> 16;   // RNE
  return (short)u;
}

// prep (mode 3): Wt = bf16 W^T re-laid for the 32x32 GEMM:
//   16B chunk addr = ((tc*64 + ks)*64 + sh*32 + c)*8 shorts holds slots
//   s = ks*16 + sh*8 + [0,8) for col co = tc*32 + c  (one contiguous 1KB line
//   per wave per k-step). Slot->k perm matches conv s_agg: slot s = ct*256 +
//   m*16 + q*4 + r  holds  k = ct*256 + q*64 + r*16 + m.
// fbf = channel-interleaved bf16 features; l2bf/l3bf = bf16 MLP weights;
// Gc4 = collapsed layer-1; out tail = opts copy.
__global__ __launch_bounds__(256) void prep_kernel(
    const float* __restrict__ weight, const float* __restrict__ opts,
    const float* __restrict__ feats, const float* __restrict__ centers,
    const float* __restrict__ l1_w, const float* __restrict__ l1_b,
    const float* __restrict__ l2_w, const float* __restrict__ l3_w,
    short* __restrict__ Wt, short* __restrict__ fbf,
    short* __restrict__ l2bf, short* __restrict__ l3bf, float* __restrict__ Gc4,
    float* __restrict__ out_tail, int mode) {
  int tid = blockIdx.x * 256 + threadIdx.x;
  if (mode >= 1 && tid < NWT) {
    int co, s;
    if (mode == 3) {
      // decode 32x32-tile slot: tid = (((tc*64+ks)*64) + sh*32 + c)*8 + e
      int e = tid & 7, c = (tid >> 3) & 31, sh = (tid >> 8) & 1;
      int ks = (tid >> 9) & 63, tc = tid >> 15;
      co = tc * 32 + c;
      s = ks * 16 + sh * 8 + e;
    } else {
      co = tid >> 10;
      s = tid & 1023;
    }
    int k;
    if (mode == 3) {  // slot s -> k permutation (matches conv s_agg layout)
      int r = s & 3, q = (s >> 2) & 3, m = (s >> 4) & 15, ct = s >> 8;
      k = ct * 256 + q * 64 + r * 16 + m;
    } else {
      k = s;
    }
    Wt[tid] = f2bf(weight[(size_t)k * COUT + co]);
  }
  if (mode >= 2 && tid < NFBF / 4) {
    // thread = (row, lr): reads feats[row][lr + 16*ct], writes 4 adjacent shorts
    int row = tid >> 4, lr = tid & 15;
    const float* fr = feats + ((size_t)row << 6) + lr;
    short4v v = {f2bf(fr[0]), f2bf(fr[16]), f2bf(fr[32]), f2bf(fr[48])};
    *(short4v*)(fbf + ((size_t)row << 6) + lr * 4) = v;
  }
  if (mode == 3) {
    if (tid < 512) l2bf[tid] = f2bf(l2_w[tid]);   // [16 out][32 in]
    if (tid < 256) l3bf[tid] = f2bf(l3_w[tid]);   // [16 out][16 in]
    if (tid < 32) {
      float g0 = 0.f, g1 = 0.f, g2 = 0.f, cc = l1_b[tid];
      const float* wr = l1_w + tid * 48;
#pragma unroll
      for (int m = 0; m < 16; ++m) { g0 += wr[m]; g1 += wr[16 + m]; g2 += wr[32 + m]; }
#pragma unroll
      for (int i = 0; i < 48; ++i) cc -= wr[i] * centers[i];
      Gc4[tid * 4 + 0] = g0; Gc4[tid * 4 + 1] = g1; Gc4[tid * 4 + 2] = g2; Gc4[tid * 4 + 3] = cc;
    }
  }
  if (tid < BATCH * NPTS * 3) out_tail[tid] = opts[tid];
}

// Fused kernel, 512 threads / 32 points per block:
//   phase 0-2: per-neighbor MLP, phase-batched (unchanged, round-9-verified).
//   phase 3:   output GEMM [32 x 1024] @ [1024 x 128] on 32x32x16 MFMA:
//              8 waves = 4 col-tiles x 2 K-halves. Per wave 32 MFMA + 32
//              ds_read_b128 (HALF the LDS A-traffic of the 16x16 version —
//              the GEMM was LDS-read-bound: 64 b128 ~770cy vs 64 MFMA ~310cy).
//              K-halves reduced via f32 partials in dead s_agg space.
// LDS 66 KB -> 2 blocks/CU.
__global__ __launch_bounds__(512, 4) void conv_kernel(
    const int* __restrict__ indices, const short* __restrict__ fbf,
    const short* __restrict__ Wt, const short* __restrict__ l2bf,
    const short* __restrict__ l3bf, const float* __restrict__ Gc4,
    const float* __restrict__ l2_b, const float* __restrict__ l3_b,
    const float* __restrict__ input_pts, const float* __restrict__ output_pts,
    const float* __restrict__ bias, float* __restrict__ out) {
  __shared__ __align__(16) short s_agg[PTSC * AGG_STRIDE];   // 66048 B

  const int t = threadIdx.x, blk = blockIdx.x;               // 2048 blocks
  // XCD swizzle: batch = blk&7 -> each batch's fbf (1 MB) pinned to one XCD L2
  const int w = ((blk & 7) << 8) | (blk >> 3);
  const int batch = w >> 8, n0 = (w & 255) * PTSC;
  const int lane = t & 63, wv = t >> 6, quad = lane >> 4, lrow = lane & 15;
  const size_t bbase = (size_t)batch * NPTS;

  // thread t <-> (pt = wv*4+quad, nbr = lrow): own neighbor id + relative position
  const int myid = indices[(bbase + n0) * KNN + t];
  const float* op = output_pts + (bbase + n0 + wv * 4 + quad) * 3;
  const float* ip = input_pts + (bbase + myid) * 3;
  const float px = ip[0] - op[0], py = ip[1] - op[1], pz = ip[2] - op[2];

  // per-lane constants: collapsed-L1 rows; W2 A-frag; W3^T B-frag; biases in MFMA C-layout
  f32x4 G[8];
#pragma unroll
  for (int j = 0; j < 8; ++j) G[j] = *(const f32x4*)(Gc4 + (quad * 8 + j) * 4);
  const short8  w2f = *(const short8*)(l2bf + lrow * 32 + quad * 8);
  const short4v w3f = *(const short4v*)(l3bf + lrow * 16 + quad * 4);
  const f32x4 b2f = *(const f32x4*)(l2_b + quad * 4);
  const float b3v = l3_b[lrow];
  const f32x4 b3f = {b3v, b3v, b3v, b3v};      // layer3 swapped: C[row=nbr][col=m] = b3[m]

  // all 16 feature gathers upfront (ids via in-wave shuffle of myid; 16 L2 loads
  // in flight, latency hidden under the h1 VALU block below)
  short4v g[4][4];
#pragma unroll
  for (int pp = 0; pp < 4; ++pp)
#pragma unroll
    for (int j = 0; j < 4; ++j) {
      const int idn = __shfl(myid, pp * 16 + quad * 4 + j);
      g[pp][j] = *(const short4v*)(fbf + ((bbase + idn) << 6) + lrow * 4);
    }

  // ---- h1 for all 4 points (pure VALU; B-frag layout [k=q*8+j][nbr=lrow]) ----
  short8 h1f[4];
#pragma unroll
  for (int pp = 0; pp < 4; ++pp) {
    const float qx = __shfl(px, pp * 16 + lrow);
    const float qy = __shfl(py, pp * 16 + lrow);
    const float qz = __shfl(pz, pp * 16 + lrow);
#pragma unroll
    for (int j = 0; j < 8; ++j) {
      const f32x4 Gx = G[j];
      h1f[pp][j] = f2bf(fmaxf(fmaf(Gx[0], qx, fmaf(Gx[1], qy, fmaf(Gx[2], qz, Gx[3]))), 0.f));
    }
  }

  // ---- layer2 x4 (independent MFMAs): D[h2feat=q*4+r][nbr=lrow] = W2@h1 + b2 ----
  f32x4 h2[4];
#pragma unroll
  for (int pp = 0; pp < 4; ++pp)
    h2[pp] = __builtin_amdgcn_mfma_f32_16x16x32_bf16(w2f, h1f[pp], b2f, 0, 0, 0);
  short4v h2f[4];
#pragma unroll
  for (int pp = 0; pp < 4; ++pp)
#pragma unroll
    for (int r = 0; r < 4; ++r) h2f[pp][r] = f2bf(fmaxf(h2[pp][r], 0.f));

  // ---- layer3 x4 SWAPPED: D = H2^T @ W3^T + b3 -> D[nbr=q*4+r][m=lrow] ----
  f32x4 h3[4];
#pragma unroll
  for (int pp = 0; pp < 4; ++pp)
    h3[pp] = __builtin_amdgcn_mfma_f32_16x16x16bf16_1k(h2f[pp], w3f, b3f, 0, 0, 0);
  short4v dfr[4];   // relu + /K fold; this IS the agg B-frag
#pragma unroll
  for (int pp = 0; pp < 4; ++pp)
#pragma unroll
    for (int r = 0; r < 4; ++r) dfr[pp][r] = f2bf(fmaxf(h3[pp][r], 0.f) * 0.0625f);

  // ---- agg: 16 independent MFMAs -> s_agg ----
#pragma unroll
  for (int pp = 0; pp < 4; ++pp) {
    const int pt = wv * 4 + pp;
    const short4v g0 = g[pp][0], g1 = g[pp][1], g2 = g[pp][2], g3 = g[pp][3];
#pragma unroll
    for (int ct = 0; ct < 4; ++ct) {
      const short4v afr = {g0[ct], g1[ct], g2[ct], g3[ct]};
      const f32x4 dd = __builtin_amdgcn_mfma_f32_16x16x16bf16_1k(
          afr, dfr[pp], (f32x4){0.f, 0.f, 0.f, 0.f}, 0, 0, 0);
      short4v sv;
#pragma unroll
      for (int r = 0; r < 4; ++r) sv[r] = f2bf(dd[r]);
      // slot = ct*256 + m*16 + q*4 + r  (contiguous b64; 4 dw/bank uniform)
      *(short4v*)&s_agg[pt * AGG_STRIDE + ct * 256 + lrow * 16 + quad * 4] = sv;
    }
  }

  // ---- pre-barrier Wt prefetch (stays in flight across the barrier) ----
  // 32x32 decomposition: wave = (K-half kh, col-tile tc); lane = (col, k-subgroup sh)
  const int kh = wv >> 2, tc = wv & 3;
  const int col = lane & 31, sh = lane >> 5;
  const short* wp = Wt + ((tc * 64 + kh * 32) * 64 + sh * 32 + col) * 8;  // +ks*512
  const short* ap = s_agg + col * AGG_STRIDE + kh * 512 + sh * 8;         // +ks*16
  short8 Bpf[4];
#pragma unroll
  for (int i = 0; i < 4; ++i) Bpf[i] = *(const short8*)(wp + i * 512);

  asm volatile("s_waitcnt lgkmcnt(0)" ::: "memory");   // s_agg writes visible
  __builtin_amdgcn_s_barrier();
  asm volatile("" ::: "memory");                       // fence: no ds_read hoist

  // ---- phase 3: 32 x mfma_32x32x16; A = s_agg rows (row=lane&31), B = Wt tile ----
  f32x16 acc;
#pragma unroll
  for (int i = 0; i < 16; ++i) acc[i] = 0.f;
  __builtin_amdgcn_s_setprio(1);
#pragma unroll
  for (int ks = 0; ks < 32; ++ks) {
    const short8 bfr = Bpf[ks & 3];
    if (ks < 28) Bpf[ks & 3] = *(const short8*)(wp + (ks + 4) * 512);
    const short8 av = *(const short8*)(ap + ks * 16);
    acc = __builtin_amdgcn_mfma_f32_32x32x16_bf16(av, bfr, acc, 0, 0, 0);
  }
  __builtin_amdgcn_s_setprio(0);

  // ---- K-half reduce via f32 partials in (now dead) s_agg; stride 20 floats:
  //      16B-aligned per lane, banks spread (20L mod 32 cycles 8 starts) ----
  __builtin_amdgcn_s_barrier();                        // all A-reads consumed
  asm volatile("" ::: "memory");
  float* ps = (float*)s_agg;
  if (kh == 1) {
#pragma unroll
    for (int r4 = 0; r4 < 4; ++r4) {
      const f32x4 v = {acc[r4 * 4], acc[r4 * 4 + 1], acc[r4 * 4 + 2], acc[r4 * 4 + 3]};
      *(f32x4*)(ps + tc * 1280 + lane * 20 + r4 * 4) = v;
    }
  }
  asm volatile("s_waitcnt lgkmcnt(0)" ::: "memory");
  __builtin_amdgcn_s_barrier();
  asm volatile("" ::: "memory");
  if (kh == 0) {
    const float bi = bias[tc * 32 + col];
    f32x4 pr[4];
#pragma unroll
    for (int r4 = 0; r4 < 4; ++r4)
      pr[r4] = *(const f32x4*)(ps + tc * 1280 + lane * 20 + r4 * 4);
    // D layout (m74/m101): col = lane&31, row = (reg&3) + 8*(reg>>2) + 4*sh
#pragma unroll
    for (int reg = 0; reg < 16; ++reg) {
      const int row = (reg & 3) + 8 * (reg >> 2) + 4 * sh;
      out[(bbase + n0 + row) * COUT + tc * 32 + col] = acc[reg] + pr[reg >> 2][reg & 3] + bi;
    }
  }
}

// ---------------- fallback monolithic kernel, small workspace ----------------
// (modes 0-2 only; uses the old co-major Wt layout which prep still writes there)
template <int MODE>
__global__ __launch_bounds__(256, 3) void ptconv_mono(
    const float* __restrict__ features, const float* __restrict__ input_pts,
    const float* __restrict__ output_pts, const int* __restrict__ indices,
    const float* __restrict__ centers, const float* __restrict__ weight,
    const float* __restrict__ bias,
    const float* __restrict__ l1_w, const float* __restrict__ l1_b,
    const float* __restrict__ l2_w, const float* __restrict__ l2_b,
    const float* __restrict__ l3_w, const float* __restrict__ l3_b,
    const short* __restrict__ Wt, const short* __restrict__ fbf,
    float* __restrict__ out) {
  __shared__ __align__(16) short s_dT[MD * DT_STR];
  __shared__ __align__(16) short s_agg[PTS * AGG_STRIDE];
  __shared__ __align__(16) int   s_idx[PTS * KNN];

  const int t = threadIdx.x;
  const int blk = blockIdx.x;
  const int batch = blk >> 9;
  const int n0 = (blk & 511) * PTS;
  const int lane = t & 63;
  const int wv = t >> 6;
  const int quad = lane >> 4;
  const int lrow = lane & 15;

  s_idx[t] = indices[((size_t)batch * NPTS + n0) * KNN + t];
  {
    const int pt = t >> 4;
    const int id = s_idx[t];
    const float* op = &output_pts[((size_t)batch * NPTS + n0 + pt) * 3];
    const float* ip = &input_pts[((size_t)batch * NPTS + id) * 3];
    const float px = ip[0] - op[0], py = ip[1] - op[1], pz = ip[2] - op[2];
    f32x2 dv[24];
    {
      const f32x2 px2 = {px, px}, py2 = {py, py}, pz2 = {pz, pz};
      const f32x2* cx = (const f32x2*)centers;
      const f32x2* cy = (const f32x2*)(centers + 16);
      const f32x2* cz = (const f32x2*)(centers + 32);
#pragma unroll
      for (int i = 0; i < 8; ++i) {
        dv[i] = px2 - cx[i]; dv[8 + i] = py2 - cy[i]; dv[16 + i] = pz2 - cz[i];
      }
    }
    float h1[32];
#pragma unroll
    for (int o = 0; o < 32; ++o) {
      const f32x2* wr = (const f32x2*)(l1_w + o * 48);
      f32x2 acc = {0.f, 0.f};
#pragma unroll
      for (int i = 0; i < 24; ++i) acc += dv[i] * wr[i];
      h1[o] = fmaxf(acc[0] + acc[1] + l1_b[o], 0.f);
    }
    f32x2 h1v[16];
#pragma unroll
    for (int i = 0; i < 16; ++i) h1v[i] = (f32x2){h1[2 * i], h1[2 * i + 1]};
    float h2[16];
#pragma unroll
    for (int o = 0; o < 16; ++o) {
      const f32x2* wr = (const f32x2*)(l2_w + o * 32);
      f32x2 acc = {0.f, 0.f};
#pragma unroll
      for (int i = 0; i < 16; ++i) acc += h1v[i] * wr[i];
      h2[o] = fmaxf(acc[0] + acc[1] + l2_b[o], 0.f);
    }
    f32x2 h2v[8];
#pragma unroll
    for (int i = 0; i < 8; ++i) h2v[i] = (f32x2){h2[2 * i], h2[2 * i + 1]};
#pragma unroll
    for (int o = 0; o < 16; ++o) {
      const f32x2* wr = (const f32x2*)(l3_w + o * 16);
      f32x2 acc = {0.f, 0.f};
#pragma unroll
      for (int i = 0; i < 8; ++i) acc += h2v[i] * wr[i];
      s_dT[o * DT_STR + t] = f2bf(fmaxf(acc[0] + acc[1] + l3_b[o], 0.f));
    }
  }
  __syncthreads();
  {
#pragma unroll
    for (int pp = 0; pp < 4; ++pp) {
      const int pt = wv * 4 + pp;
      const short4v bfrag = *(const short4v*)&s_dT[lrow * DT_STR + pt * 16 + quad * 4];
      const int4 idx4 = *(const int4*)&s_idx[pt * 16 + quad * 4];
#pragma unroll
      for (int ct = 0; ct < 4; ++ct) {
        short4v afr;
#pragma unroll
        for (int j = 0; j < 4; ++j) {
          const int id = ((const int*)&idx4)[j];
          const size_t base = ((size_t)batch * NPTS + id) * CIN;
          if (MODE >= 2) afr[j] = fbf[base + lrow * 4 + ct];      // interleaved layout
          else           afr[j] = f2bf(features[base + ct * 16 + lrow]);
        }
        f32x4 dd = __builtin_amdgcn_mfma_f32_16x16x16bf16_1k(
            afr, bfrag, (f32x4){0.f, 0.f, 0.f, 0.f}, 0, 0, 0);
#pragma unroll
        for (int r = 0; r < 4; ++r) {
          const int rr = (r + quad) & 3;
          const int c = ct * 16 + quad * 4 + rr;
          s_agg[pt * AGG_STRIDE + c * 16 + lrow] = f2bf(dd[rr]);
        }
      }
    }
  }
  __syncthreads();
  {
    f32x4 acc0 = {0.f, 0.f, 0.f, 0.f};
    f32x4 acc1 = {0.f, 0.f, 0.f, 0.f};
    const int co0 = wv * 32 + lrow;
    const int co1 = co0 + 16;
    const short* arow = s_agg + lrow * AGG_STRIDE + quad * 8;
#pragma unroll 4
    for (int kb = 0; kb < 32; ++kb) {
      const short8 a = *(const short8*)(arow + kb * 32);
      short8 b0, b1;
      if (MODE >= 1) {
        b0 = *(const short8*)(Wt + (size_t)co0 * 1024 + kb * 32 + quad * 8);
        b1 = *(const short8*)(Wt + (size_t)co1 * 1024 + kb * 32 + quad * 8);
      } else {
#pragma unroll
        for (int j = 0; j < 8; ++j) {
          const int kk = kb * 32 + quad * 8 + j;
          b0[j] = f2bf(weight[(size_t)kk * COUT + co0]);
          b1[j] = f2bf(weight[(size_t)kk * COUT + co1]);
        }
      }
      acc0 = __builtin_amdgcn_mfma_f32_16x16x32_bf16(a, b0, acc0, 0, 0, 0);
      acc1 = __builtin_amdgcn_mfma_f32_16x16x32_bf16(a, b1, acc1, 0, 0, 0);
    }
    const float bi0 = bias[co0], bi1 = bias[co1];
#pragma unroll
    for (int r = 0; r < 4; ++r) {
      const int pt = quad * 4 + r;
      const size_t rowo = ((size_t)batch * NPTS + n0 + pt) * COUT;
      out[rowo + co0] = acc0[r] * 0.0625f + bi0;
      out[rowo + co1] = acc1[r] * 0.0625f + bi1;
    }
  }
}

extern "C" void kernel_launch(void* const* d_in, const int* in_sizes, int n_in,
                              void* d_out, int out_size, void* d_ws, size_t ws_size,
                              hipStream_t stream) {
  const float* features   = (const float*)d_in[0];
  const float* input_pts  = (const float*)d_in[1];
  const float* output_pts = (const float*)d_in[2];
  const int*   indices    = (const int*)d_in[3];
  const float* centers    = (const float*)d_in[4];
  const float* weight     = (const float*)d_in[5];
  const float* bias       = (const float*)d_in[6];
  const float* l1_w       = (const float*)d_in[7];
  const float* l1_b       = (const float*)d_in[8];
  const float* l2_w       = (const float*)d_in[9];
  const float* l2_b       = (const float*)d_in[10];
  const float* l3_w       = (const float*)d_in[11];
  const float* l3_b       = (const float*)d_in[12];
  float* out = (float*)d_out;

  short* Wt   = (short*)d_ws;
  short* fbf  = Wt + NWT;
  short* l2bf = fbf + NFBF;
  short* l3bf = l2bf + 512;
  float* Gc4  = (float*)(l3bf + 256);       // 128 floats (base 16B aligned)
  const size_t need3 = (size_t)(NWT + NFBF + 512 + 256) * 2 + 512;

  int mode = 0;
  if (ws_size >= need3) mode = 3;
  else if (ws_size >= (size_t)(NWT + NFBF) * 2) mode = 2;
  else if (ws_size >= (size_t)NWT * 2) mode = 1;

  float* out_tail = out + (size_t)BATCH * NPTS * COUT;
  const int prep_elems = (mode >= 2) ? (NFBF / 4) : BATCH * NPTS * 3;
  prep_kernel<<<(prep_elems + 255) / 256, 256, 0, stream>>>(
      weight, output_pts, features, centers, l1_w, l1_b, l2_w, l3_w,
      Wt, fbf, l2bf, l3bf, Gc4, out_tail, mode);

  if (mode == 3) {
    conv_kernel<<<NPTS_G / PTSC, 512, 0, stream>>>(
        indices, fbf, Wt, l2bf, l3bf, Gc4, l2_b, l3_b, input_pts, output_pts, bias, out);
  } else if (mode == 2) {
    ptconv_mono<2><<<NPTS_G / PTS, 256, 0, stream>>>(features, input_pts, output_pts, indices,
        centers, weight, bias, l1_w, l1_b, l2_w, l2_b, l3_w, l3_b, Wt, fbf, out);
  } else if (mode == 1) {
    ptconv_mono<1><<<NPTS_G / PTS, 256, 0, stream>>>(features, input_pts, output_pts, indices,
        centers, weight, bias, l1_w, l1_b, l2_w, l2_b, l3_w, l3_b, Wt, fbf, out);
  } else {
    ptconv_mono<0><<<NPTS_G / PTS, 256, 0, stream>>>(features, input_pts, output_pts, indices,
        centers, weight, bias, l1_w, l1_b, l2_w, l2_b, l3_w, l3_b, Wt, fbf, out);
  }
}